// Round 7
// baseline (244.457 us; speedup 1.0000x reference)
//
#include <hip/hip_runtime.h>

// spikes = (floor(v0 + cumsum(relu(x)*DT)) - floor(prev)) / DT, f64 scan.
// (f32 scan flips floors vs the f64 np reference — R0/R1; f64 segment
// reassociation ~1e-16, validated absmax 0.0 in R3/R4/R6.)
//
// History: R3 fused 16-seg, 2x input read = 57.4us. R4 two-kernel = 64us
// (launch overhead). R5 nontemporal stores = 102us (WRITE_SIZE +69% — write
// amplification; never nt-store). R6 2x wave pool = 57.7us (NO change →
// not wave-starved; aggregate traffic ceiling ~7 TB/s is binding:
// 402 MB / 57.4us = 7.0 TB/s = fillBuffer's ceiling).
//
// R7: cut traffic 402 -> 268 MB. TSEG=32 so each thread's whole segment
// stays REGISTER-resident across the barrier: load once, sum, prefix, emit
// from regs. No phase-2 re-read. Floor at 7 TB/s aggregate = ~38us.

#pragma clang fp contract(off)   // np rounds rate before accumulating: no FMA

constexpr int B = 16;
constexpr int T = 2048;
constexpr int D = 1024;
constexpr int NSEG = 64;          // segments along T
constexpr int TSEG = T / NSEG;    // 32 steps per segment (register-resident)
constexpr int CPB = 16;           // chains per block
constexpr int SPW = 4;            // segments per wave (64 lanes / 16 chains)

__global__ __launch_bounds__(1024, 8)   // cap VGPR at 64 -> 32 waves/CU
void spike_scan_kernel(const float* __restrict__ in,
                       const float* __restrict__ state,
                       float* __restrict__ out) {
  const int lane = threadIdx.x & 63;
  const int wave = threadIdx.x >> 6;              // 0..15
  const int sub  = lane & 15;                     // chain within block
  const int seg  = wave * SPW + (lane >> 4);      // segment 0..63

  const int c = blockIdx.x * CPB + sub;           // chain id
  const int b = c >> 10;                          // D = 1024
  const int d = c & (D - 1);
  const size_t base = (size_t)b * T * D + d + (size_t)seg * TSEG * D;
  const float* __restrict__ ip = in + base;
  float* __restrict__ op = out + base;

  __shared__ double segsum[NSEG][CPB];            // 8 KB

  // ---- Load the whole segment into registers (the ONLY input read) ----
  float buf[TSEG];
#pragma unroll
  for (int u = 0; u < TSEG; ++u) buf[u] = ip[(size_t)u * D];

  // ---- Phase 1: in-order f64 segment sum ----
  double ssum = 0.0;
#pragma unroll
  for (int u = 0; u < TSEG; ++u)
    ssum += (double)fmaxf(buf[u], 0.0f) * 0.001;
  segsum[seg][sub] = ssum;
  __syncthreads();

  // ---- Phase 2: in-order prefix over preceding segments, emit from regs ----
  const double v0 = (double)state[c];
  double s = 0.0;
  for (int w = 0; w < seg; ++w) s += segsum[w][sub];
  double prev = floor(v0 + s);                    // seg 0: floor(v0)

#pragma unroll
  for (int u = 0; u < TSEG; ++u) {
    s += (double)fmaxf(buf[u], 0.0f) * 0.001;
    const double fl = floor(v0 + s);
    op[(size_t)u * D] = (float)((fl - prev) * 1000.0);
    prev = fl;
  }
}

extern "C" void kernel_launch(void* const* d_in, const int* in_sizes, int n_in,
                              void* d_out, int out_size, void* d_ws, size_t ws_size,
                              hipStream_t stream) {
  const float* in = (const float*)d_in[0];     // [B, T, D] f32
  const float* st = (const float*)d_in[1];     // [B, D]    f32
  float* out = (float*)d_out;                  // [B, T, D] f32

  // 16384 chains / 16 per block = 1024 blocks x 1024 threads (16 waves).
  dim3 grid(B * D / CPB);
  dim3 block(1024);
  spike_scan_kernel<<<grid, block, 0, stream>>>(in, st, out);
}

// Round 8
// 78.509 us; speedup vs baseline: 3.1137x; 3.1137x over previous
//
#include <hip/hip_runtime.h>

// spikes = (floor(v0 + cumsum(relu(x)*DT)) - floor(prev)) / DT, f64 scan.
// (f32 scan flips floors vs the f64 np reference — R0/R1; f64 segment
// reassociation ~1e-16, validated absmax 0.0 in R3/R4/R6/R7.)
//
// History: R3 fused 16-seg 2x-read = 57.4us; R6 2x wave pool = 57.7us
// (NOT wave-starved; ~7 TB/s aggregate traffic ceiling binding).
// R7 single-read register-staged, __launch_bounds__(1024,8): VGPR capped
// at 64 -> buf[32] SPILLED to scratch (VGPR=32, WRITE 131->568 MB, 244us).
// R8 = R7 with bounds (1024,4): VGPR cap 128, no spill, 16 waves/CU
// (R6 proved more waves don't help). Traffic 402 -> 268 MB, floor ~38us.

#pragma clang fp contract(off)   // np rounds rate before accumulating: no FMA

constexpr int B = 16;
constexpr int T = 2048;
constexpr int D = 1024;
constexpr int NSEG = 64;          // segments along T
constexpr int TSEG = T / NSEG;    // 32 steps per segment (register-resident)
constexpr int CPB = 16;           // chains per block
constexpr int SPW = 4;            // segments per wave (64 lanes / 16 chains)

__global__ __launch_bounds__(1024, 4)   // VGPR cap 128: buf must NOT spill
void spike_scan_kernel(const float* __restrict__ in,
                       const float* __restrict__ state,
                       float* __restrict__ out) {
  const int lane = threadIdx.x & 63;
  const int wave = threadIdx.x >> 6;              // 0..15
  const int sub  = lane & 15;                     // chain within block
  const int seg  = wave * SPW + (lane >> 4);      // segment 0..63

  const int c = blockIdx.x * CPB + sub;           // chain id
  const int b = c >> 10;                          // D = 1024
  const int d = c & (D - 1);
  const size_t base = (size_t)b * T * D + d + (size_t)seg * TSEG * D;
  const float* __restrict__ ip = in + base;
  float* __restrict__ op = out + base;

  __shared__ double segsum[NSEG][CPB];            // 8 KB

  // ---- Load the whole segment into registers (the ONLY input read) ----
  float buf[TSEG];
#pragma unroll
  for (int u = 0; u < TSEG; ++u) buf[u] = ip[(size_t)u * D];

  // ---- Phase 1: in-order f64 segment sum ----
  double ssum = 0.0;
#pragma unroll
  for (int u = 0; u < TSEG; ++u)
    ssum += (double)fmaxf(buf[u], 0.0f) * 0.001;
  segsum[seg][sub] = ssum;
  __syncthreads();

  // ---- Phase 2: in-order prefix over preceding segments, emit from regs ----
  const double v0 = (double)state[c];
  double s = 0.0;
  for (int w = 0; w < seg; ++w) s += segsum[w][sub];
  double prev = floor(v0 + s);                    // seg 0: floor(v0)

#pragma unroll
  for (int u = 0; u < TSEG; ++u) {
    s += (double)fmaxf(buf[u], 0.0f) * 0.001;
    const double fl = floor(v0 + s);
    op[(size_t)u * D] = (float)((fl - prev) * 1000.0);
    prev = fl;
  }
}

extern "C" void kernel_launch(void* const* d_in, const int* in_sizes, int n_in,
                              void* d_out, int out_size, void* d_ws, size_t ws_size,
                              hipStream_t stream) {
  const float* in = (const float*)d_in[0];     // [B, T, D] f32
  const float* st = (const float*)d_in[1];     // [B, D]    f32
  float* out = (float*)d_out;                  // [B, T, D] f32

  // 16384 chains / 16 per block = 1024 blocks x 1024 threads (16 waves).
  dim3 grid(B * D / CPB);
  dim3 block(1024);
  spike_scan_kernel<<<grid, block, 0, stream>>>(in, st, out);
}